// Round 2
// baseline (14042.247 us; speedup 1.0000x reference)
//
#include <hip/hip_runtime.h>

// ---------------------------------------------------------------------------
// PVRNNLayer: B=128, T=1000, D=256, Z=32, IN=256.
// Float I/O dtype (bf16 vs fp32) is detected at runtime from the bit patterns
// of hd (values ~N(0,1)): a detector kernel writes a flag into d_ws; all
// kernels branch uniformly on it via ldf()/stf().
//
// out layout: d_seq [B][T][D] (32,768,000 elems), sum_wkls (1), wnll (1)
// k1: hdW[m][j] = bias[j] + sum_k hd[m][k]*Whd2h[j][k], stored IN-PLACE into
//     out's d_seq region (read then overwritten by k2 — same thread, address-
//     disjoint: reads index t+1 happen one iteration before writes index t+1).
// k2: persistent scan, 1 block / batch row, recurrent weights in registers.
// k3: finalize the two scalars.
// ---------------------------------------------------------------------------

#define BB 128
#define TT 1000
#define NSEQ 32768000
#define KEPS 1e-6f

__device__ __forceinline__ float bfu(unsigned short u) {
    union { unsigned int i; float f; } v; v.i = ((unsigned int)u) << 16; return v.f;
}
__device__ __forceinline__ unsigned short f2bf(float f) {   // RNE
    union { float f; unsigned int i; } v; v.f = f;
    unsigned int x = v.i;
    return (unsigned short)((x + 0x7fffu + ((x >> 16) & 1u)) >> 16);
}
__device__ __forceinline__ float ldf(const void* p, size_t i, int bf) {
    return bf ? bfu(((const unsigned short*)p)[i]) : ((const float*)p)[i];
}
__device__ __forceinline__ void stf(void* p, size_t i, float v, int bf) {
    if (bf) ((unsigned short*)p)[i] = f2bf(v);
    else    ((float*)p)[i] = v;
}

// ---------------------------------------------------------------------------
// k0: dtype detector.  bf16 N(0,1) data -> nearly all ushorts have exponent
// bits in [112,134]; fp32 data -> only the odd (high) halves do (~55% total).
// ---------------------------------------------------------------------------
__global__ __launch_bounds__(256) void k0_detect(
    const unsigned short* __restrict__ hd, int* __restrict__ flag)
{
    __shared__ int cnt;
    if (threadIdx.x == 0) cnt = 0;
    __syncthreads();
    int c = 0;
    for (int i = threadIdx.x; i < 2048; i += 256) {
        unsigned short u = hd[i];
        int e = (u >> 7) & 0xFF;
        c += ((e >= 112 && e <= 134) || ((u & 0x7FFF) == 0)) ? 1 : 0;
    }
    atomicAdd(&cnt, c);
    __syncthreads();
    if (threadIdx.x == 0) flag[0] = (cnt > 1700) ? 1 : 0;
}

// ---------------------------------------------------------------------------
// k1: hdW = hd @ Whd2h^T + bias -> out (d_seq region).  grid 4000 x 256 thr.
// Each block: 32 rows (m) x all 256 cols (j = tid).
// ---------------------------------------------------------------------------
__global__ __launch_bounds__(256) void k1_gemm(
    const void* __restrict__ hd,
    const void* __restrict__ W,       // Whd2h [256][256]
    const void* __restrict__ bias,
    void* __restrict__ out,
    const int* __restrict__ flagp)
{
    const int bf = flagp[0];
    __shared__ __align__(16) float hdS[32][36];   // 36: keeps 16B align, pads banks
    const int tid = threadIdx.x;
    const int j = tid;
    const long m0 = (long)blockIdx.x * 32;
    const int lm = tid >> 3;
    const int lk = (tid & 7) * 4;

    float acc[32];
#pragma unroll
    for (int m = 0; m < 32; m++) acc[m] = 0.f;

    for (int kc = 0; kc < 256; kc += 32) {
        float stage[4];
#pragma unroll
        for (int q = 0; q < 4; q++)
            stage[q] = ldf(hd, (size_t)(m0 + lm) * 256 + kc + lk + q, bf);
        float w[32];
#pragma unroll
        for (int u = 0; u < 32; u++)
            w[u] = ldf(W, (size_t)j * 256 + kc + u, bf);
        __syncthreads();                 // previous chunk fully consumed
#pragma unroll
        for (int q = 0; q < 4; q++) hdS[lm][lk + q] = stage[q];
        __syncthreads();
#pragma unroll
        for (int m = 0; m < 32; m++) {
            float s = 0.f;
#pragma unroll
            for (int k4 = 0; k4 < 8; k4++) {
                float4 a = *(const float4*)&hdS[m][k4 * 4];
                s += a.x*w[k4*4+0] + a.y*w[k4*4+1] + a.z*w[k4*4+2] + a.w*w[k4*4+3];
            }
            acc[m] += s;
        }
    }
    float bj = ldf(bias, (size_t)j, bf);
#pragma unroll
    for (int m = 0; m < 32; m++)
        stf(out, (size_t)(m0 + m) * 256 + j, acc[m] + bj, bf);
}

// ---------------------------------------------------------------------------
// k2: persistent recurrent scan.  grid = 128, block = 512.
// thread -> (j = tid&255, half = tid>>8) splits K of Wd2h;
// dz split as (dzi = tid&63, seg = tid>>6).  Weights in fp32 registers.
// ---------------------------------------------------------------------------
__global__ __launch_bounds__(512) void k2_scan(
    const void* __restrict__ A,
    const void* __restrict__ in_p0,
    const void* __restrict__ noise,
    const void* __restrict__ Wd2h,
    const void* __restrict__ Wz2h,
    const void* __restrict__ Wd2z,
    const void* __restrict__ init_h,
    void* __restrict__ out,            // holds hdW, overwritten with d
    float* __restrict__ ws_kl,
    const int* __restrict__ flagp)
{
    const int bf = flagp[0];
    const int b = blockIdx.x;
    const int tid = threadIdx.x;
    const int j = tid & 255;
    const int half = tid >> 8;
    const int dzi = tid & 63;
    const int seg = tid >> 6;          // 0..7

    __shared__ __align__(16) float dS[256];
    __shared__ float dzp[8][64];
    __shared__ float ps[64];
    __shared__ float qs[64];
    __shared__ __align__(16) float zS[32];
    __shared__ float pp[2][256];

    // ---- weight preload (scalar loads -> fp32 registers) ----
    float wdh[128];
#pragma unroll
    for (int u = 0; u < 128; u++)
        wdh[u] = ldf(Wd2h, (size_t)j * 256 + half * 128 + u, bf);
    float wdz[32];
#pragma unroll
    for (int u = 0; u < 32; u++)
        wdz[u] = ldf(Wd2z, (size_t)dzi * 256 + seg * 32 + u, bf);
    float wzh[16];
#pragma unroll
    for (int u = 0; u < 16; u++)
        wzh[u] = ldf(Wz2h, (size_t)j * 32 + half * 16 + u, bf);

    // ---- state init ----
    float h = 0.f, decay = 0.f, invt = 0.f;
    if (half == 0) {
        float hv = ldf(init_h, (size_t)b * 256 + j, bf);
        h = hv;
        float tau = (j < 128) ? 4.f : 2.f;     // first half: 2*TAU, rest: TAU
        decay = 1.f - 1.f / tau;
        invt = 1.f / tau;
        dS[j] = tanhf(hv);
    }
    float inp0v = 0.f;
    if (tid < 64) inp0v = ldf(in_p0, (size_t)b * 64 + tid, bf);
    float kl_acc = 0.f;
    __syncthreads();

    const size_t baseA = (size_t)b * TT * 64;
    const size_t baseN = (size_t)b * TT * 32;
    const size_t baseO = (size_t)b * TT * 256;

    // prefetch for t = 0
    float hdw_p = 0.f, a_p = 0.f, n_p = 0.f;
    if (half == 0) hdw_p = ldf(out, baseO + j, bf);
    if (tid < 64)  a_p   = ldf(A, baseA + tid, bf);
    if (tid < 32)  n_p   = ldf(noise, baseN + tid, bf);

#pragma unroll 1
    for (int t = 0; t < TT; t++) {
        const float hdw_c = hdw_p, a_c = a_p, n_c = n_p;
        if (t < TT - 1) {                      // prefetch t+1
            if (half == 0) hdw_p = ldf(out, baseO + (size_t)(t + 1) * 256 + j, bf);
            if (tid < 64)  a_p   = ldf(A, baseA + (size_t)(t + 1) * 64 + tid, bf);
            if (tid < 32)  n_p   = ldf(noise, baseN + (size_t)(t + 1) * 32 + tid, bf);
        }

        // ---- phase A: matvec partials (read dS) ----
        float P = 0.f;
        const float* db = dS + half * 128;
#pragma unroll
        for (int k8 = 0; k8 < 16; k8++) {
            float4 d0 = *(const float4*)(db + k8 * 8);
            float4 d1 = *(const float4*)(db + k8 * 8 + 4);
            P += d0.x*wdh[k8*8+0] + d0.y*wdh[k8*8+1] + d0.z*wdh[k8*8+2] + d0.w*wdh[k8*8+3]
               + d1.x*wdh[k8*8+4] + d1.y*wdh[k8*8+5] + d1.z*wdh[k8*8+6] + d1.w*wdh[k8*8+7];
        }

        float Q = 0.f;
        const float* db2 = dS + seg * 32;
#pragma unroll
        for (int k4 = 0; k4 < 8; k4++) {
            float4 dv = *(const float4*)(db2 + k4 * 4);
            Q += dv.x*wdz[k4*4+0] + dv.y*wdz[k4*4+1] + dv.z*wdz[k4*4+2] + dv.w*wdz[k4*4+3];
        }
        dzp[seg][dzi] = Q;
        __syncthreads();                       // b1

        // ---- phase B1: prior / posterior (threads 0..63) ----
        if (tid < 64) {
            float dz = 0.f;
#pragma unroll
            for (int s = 0; s < 8; s++) dz += dzp[s][tid];
            float prior = (t == 0) ? inp0v : dz;
            ps[tid] = (tid < 32) ? tanhf(prior) : expf(prior);
            qs[tid] = (tid < 32) ? tanhf(a_c)   : expf(a_c);
        }
        __syncthreads();                       // b2

        // ---- phase B2: z + KL (threads 0..31) ----
        if (tid < 32) {
            float mq = qs[tid], sq = qs[tid + 32];
            float mp = ps[tid], sp = ps[tid + 32];
            zS[tid] = mq + n_c * sq;
            kl_acc += logf(sp + KEPS) - logf(sq + KEPS) - 0.5f
                    + 0.5f * (mq*mq + sq*sq - 2.f*mq*mp + mp*mp) / (sp*sp + KEPS);
        }
        __syncthreads();                       // b3

        // ---- phase C: z contribution ----
        const float* zb = zS + half * 16;
#pragma unroll
        for (int k4 = 0; k4 < 4; k4++) {
            float4 zv = *(const float4*)(zb + k4 * 4);
            P += zv.x*wzh[k4*4+0] + zv.y*wzh[k4*4+1] + zv.z*wzh[k4*4+2] + zv.w*wzh[k4*4+3];
        }
        pp[half][j] = P;
        __syncthreads();                       // b4

        // ---- phase D: h/d update + output (threads 0..255) ----
        if (half == 0) {
            float pre = pp[0][j] + pp[1][j] + hdw_c;
            h = decay * h + pre * invt;
            float dn = tanhf(h);
            dS[j] = dn;
            stf(out, baseO + (size_t)t * 256 + j, dn, bf);
        }
        __syncthreads();                       // b5
    }

    if (tid < 32) atomicAdd(ws_kl, kl_acc);
}

// ---------------------------------------------------------------------------
// k3: scalars.  out[NSEQ] = 0.001/32 * kl_sum ; out[NSEQ+1] = wnll_init_h
// ---------------------------------------------------------------------------
__global__ __launch_bounds__(256) void k3_final(
    const void* __restrict__ init_h,
    const void* __restrict__ init_mu,
    const float* __restrict__ ws_kl,
    void* __restrict__ out,
    const int* __restrict__ flagp)
{
    const int bf = flagp[0];
    __shared__ float red[256];
    const int tid = threadIdx.x;
    float s = 0.f;
    for (int i = tid; i < BB * 256; i += 256) {
        float d = ldf(init_h, (size_t)i, bf) - ldf(init_mu, (size_t)(i & 255), bf);
        s += 0.5f * d * d;
    }
    red[tid] = s;
    __syncthreads();
    for (int off = 128; off > 0; off >>= 1) {
        if (tid < off) red[tid] += red[tid + off];
        __syncthreads();
    }
    if (tid == 0) {
        float tot = red[0] + (float)(BB * 256) * 0.91893853320467274f; // 0.5*log(2*pi)
        stf(out, (size_t)NSEQ,     ws_kl[0] * (0.001f / 32.f), bf);
        stf(out, (size_t)NSEQ + 1, 0.001f * tot / 256.f, bf);
    }
}

// ---------------------------------------------------------------------------
extern "C" void kernel_launch(void* const* d_in, const int* in_sizes, int n_in,
                              void* d_out, int out_size, void* d_ws, size_t ws_size,
                              hipStream_t stream)
{
    float* wskl = (float*)d_ws;
    int*   flag = ((int*)d_ws) + 1;

    hipMemsetAsync(d_ws, 0, 8, stream);

    k0_detect<<<1, 256, 0, stream>>>((const unsigned short*)d_in[0], flag);

    // hdW = hd @ Whd2h^T + bias  -> in-place into out's d_seq region
    k1_gemm<<<(BB * TT) / 32, 256, 0, stream>>>(d_in[0], d_in[7], d_in[8],
                                                d_out, flag);

    // recurrent scan (reads hdW from out, overwrites with d)
    k2_scan<<<BB, 512, 0, stream>>>(d_in[1], d_in[2], d_in[3], d_in[4],
                                    d_in[5], d_in[6], d_in[9], d_out,
                                    wskl, flag);

    k3_final<<<1, 256, 0, stream>>>(d_in[9], d_in[10], wskl, d_out, flag);
}